// Round 2
// baseline (105452.551 us; speedup 1.0000x reference)
//
#include <hip/hip_runtime.h>
#include <math.h>

// Tacotron-style location-sensitive attention, persistent-kernel scan.
// B=16, ENC_T=512, DEC_T=1024, D=512, KW=31, PAD=15.
// 256 blocks (16 per batch element) x 512 threads, CO-RESIDENT via
// hipLaunchCooperativeKernel (plain launch gave no residency guarantee ->
// spin-barrier deadlock -> container hang).
// Thread owns one d: conv weights in 62 VGPRs, ctx[d] in a register.
// Two per-b atomic barriers per step (logits exchange, ctx exchange).

#define NBB    16   // blocks per batch element
#define BT     32   // enc_T positions per block (512/16)
#define NT     512  // threads per block
#define NBATCH 16
#define ENC_TT 512
#define DEC_TT 1024
#define DDIM   512
#define KWW    31
#define PADW   15

// workspace layout (bytes)
#define WS_BAR_CTR 0
#define WS_BAR_GEN 2048
#define WS_LOGITS  4096                          // float[16][512]
#define WS_CTXPART (4096 + NBATCH*ENC_TT*4)      // float[16][16][512]

__device__ __forceinline__ float wred_sum(float v) {
#pragma unroll
  for (int m = 1; m < 64; m <<= 1) v += __shfl_xor(v, m, 64);
  return v;
}
__device__ __forceinline__ float wred_max(float v) {
#pragma unroll
  for (int m = 1; m < 64; m <<= 1) v = fmaxf(v, __shfl_xor(v, m, 64));
  return v;
}

// Per-batch-element barrier among NBB blocks. Thread 0's agent-scope fences
// (L2 writeback / invalidate on gfx950) make cross-XCD writes visible:
// __syncthreads() has already drained every wave's stores into this XCD's L2.
__device__ __forceinline__ void bbar(int b, int* ctr, int* gen) {
  __syncthreads();
  if (threadIdx.x == 0) {
    __threadfence();  // release: write back this XCD's dirty L2 to LLC
    int* c = ctr + b * 32;
    int* g = gen + b * 32;
    int cur = __hip_atomic_load(g, __ATOMIC_RELAXED, __HIP_MEMORY_SCOPE_AGENT);
    int arrived = __hip_atomic_fetch_add(c, 1, __ATOMIC_ACQ_REL, __HIP_MEMORY_SCOPE_AGENT);
    if (arrived == NBB - 1) {
      __hip_atomic_store(c, 0, __ATOMIC_RELAXED, __HIP_MEMORY_SCOPE_AGENT);
      __hip_atomic_fetch_add(g, 1, __ATOMIC_RELEASE, __HIP_MEMORY_SCOPE_AGENT);
    } else {
      while (__hip_atomic_load(g, __ATOMIC_ACQUIRE, __HIP_MEMORY_SCOPE_AGENT) == cur)
        __builtin_amdgcn_s_sleep(2);
    }
    __threadfence();  // acquire: invalidate L1/L2 so re-reads hit fresh data
  }
  __syncthreads();
}

__global__ void __launch_bounds__(NT, 2)
attn_persistent(const float* __restrict__ enc,
                const float* __restrict__ mel,
                const int*   __restrict__ out_len,
                const float* __restrict__ w_lin,
                const float* __restrict__ w_conv,
                float* __restrict__ out_ctx,   // [16][1024][512]
                float* __restrict__ out_scr,   // [16][1024][512]
                int* bar_ctr, int* bar_gen,
                float* logits_g,               // [16][512]
                float* ctxpart_g)              // [16][16][512]
{
  const int tid  = threadIdx.x;
  const int b    = blockIdx.x / NBB;
  const int jb   = blockIdx.x % NBB;
  const int t0   = jb * BT;
  const int lane = tid & 63;
  const int wid  = tid >> 6;
  const int d    = tid;

  __shared__ float enc_lds[BT][DDIM];             // 64 KB: enc[b, t0:t0+32, :]
  __shared__ float s_arr[ENC_TT + 2 * PADW];      // score with zero halos
  __shared__ float c_arr[ENC_TT + 2 * PADW];      // cumulative score with halos
  __shared__ float red_lds[8][BT];
  __shared__ float sm8[8];
  __shared__ float bc[2];

  for (int i = tid; i < ENC_TT + 2 * PADW; i += NT) { s_arr[i] = 0.f; c_arr[i] = 0.f; }

  for (int i = tid; i < BT * DDIM; i += NT) {
    int u = i >> 9, dd = i & (DDIM - 1);
    enc_lds[u][dd] = enc[((size_t)b * ENC_TT + (t0 + u)) * DDIM + dd];
  }

  // per-thread conv weights for this d, held in VGPRs for the whole kernel
  float w0[KWW], w1[KWW];
#pragma unroll
  for (int k = 0; k < KWW; ++k) {
    w0[k] = w_conv[(size_t)d * (2 * KWW) + k];
    w1[k] = w_conv[(size_t)d * (2 * KWW) + KWW + k];
  }
  const float wld  = w_lin[d];
  const int   olen = out_len[b];

  float ctx = 0.f;
  __syncthreads();

  for (int step = 0; step < DEC_TT; ++step) {
    const float maskf = (step < olen) ? 1.f : 0.f;
    const float q = maskf * mel[((size_t)b * DEC_TT + step) * DDIM + d] + ctx;

    // ---- Phase A: conv (scatter form) + tanh + wl, for my d over 32 t's ----
    float acc[BT];
#pragma unroll
    for (int u = 0; u < BT; ++u) acc[u] = 0.f;
#pragma unroll
    for (int j = 0; j < BT + 2 * PADW; ++j) {   // 62 input positions
      const float sv = s_arr[t0 + j];           // wave-broadcast reads
      const float cv = c_arr[t0 + j];
#pragma unroll
      for (int u = 0; u < BT; ++u) {
        const int k = j - u;                    // compile-time after unroll
        if (k >= 0 && k < KWW) {
          acc[u] = fmaf(w0[k], sv, acc[u]);
          acc[u] = fmaf(w1[k], cv, acc[u]);
        }
      }
    }
#pragma unroll
    for (int u = 0; u < BT; ++u) {
      float v = wld * tanhf(q + acc[u]);
      v = wred_sum(v);                          // reduce over 64 lanes (64 d's)
      if (lane == 0) red_lds[wid][u] = v;
    }
    __syncthreads();
    if (tid < BT) {
      float s = 0.f;
#pragma unroll
      for (int w = 0; w < 8; ++w) s += red_lds[w][tid];
      logits_g[b * ENC_TT + t0 + tid] = s;
    }
    bbar(b, bar_ctr, bar_gen);                  // barrier #1: logits complete

    // ---- Phase B: softmax over 512 logits (redundant per block) ----
    const float lg = logits_g[b * ENC_TT + tid];
    float mx = wred_max(lg);
    if (lane == 0) sm8[wid] = mx;
    __syncthreads();
    if (tid == 0) {
      float m = sm8[0];
#pragma unroll
      for (int w = 1; w < 8; ++w) m = fmaxf(m, sm8[w]);
      bc[0] = m;
    }
    __syncthreads();
    const float ex = expf(lg - bc[0]);
    float sum = wred_sum(ex);
    if (lane == 0) sm8[wid] = sum;
    __syncthreads();
    if (tid == 0) {
      float s = 0.f;
#pragma unroll
      for (int w = 1; w < 8; ++w) s += sm8[w];
      bc[1] = s + sm8[0];
    }
    __syncthreads();
    const float score = ex / bc[1];
    s_arr[PADW + tid] = score;                  // becomes prev-score window
    c_arr[PADW + tid] += score;                 // cum includes current score
    if (jb == 0) out_scr[((size_t)b * DEC_TT + step) * ENC_TT + tid] = score;
    __syncthreads();

    // ---- Phase C: ctx partial over my 32 t's ----
    float part = 0.f;
#pragma unroll
    for (int u = 0; u < BT; ++u)
      part = fmaf(s_arr[PADW + t0 + u], enc_lds[u][d], part);
    ctxpart_g[((size_t)b * NBB + jb) * DDIM + d] = part;
    bbar(b, bar_ctr, bar_gen);                  // barrier #2: partials complete

    float c2 = 0.f;
#pragma unroll
    for (int jj = 0; jj < NBB; ++jj)
      c2 += ctxpart_g[((size_t)b * NBB + jj) * DDIM + d];
    ctx = c2;                                   // identical in every block of b
    if (jb == 1) out_ctx[((size_t)b * DEC_TT + step) * DDIM + d] = maskf * ctx;
  }
}

extern "C" void kernel_launch(void* const* d_in, const int* in_sizes, int n_in,
                              void* d_out, int out_size, void* d_ws, size_t ws_size,
                              hipStream_t stream) {
  const float* enc   = (const float*)d_in[0];
  const float* mel   = (const float*)d_in[1];
  const int*   olen  = (const int*)d_in[3];   // encoder_lengths (d_in[2]) unused
  const float* wlin  = (const float*)d_in[4];
  const float* wconv = (const float*)d_in[5];

  float* out_ctx = (float*)d_out;
  float* out_scr = out_ctx + (size_t)NBATCH * DEC_TT * DDIM;

  char* ws = (char*)d_ws;
  hipMemsetAsync(ws, 0, 4096, stream);  // zero barrier counters (ws is poisoned)

  int*   bar_ctr   = (int*)(ws + WS_BAR_CTR);
  int*   bar_gen   = (int*)(ws + WS_BAR_GEN);
  float* logits_g  = (float*)(ws + WS_LOGITS);
  float* ctxpart_g = (float*)(ws + WS_CTXPART);

  void* args[] = {&enc, &mel, &olen, &wlin, &wconv, &out_ctx, &out_scr,
                  &bar_ctr, &bar_gen, &logits_g, &ctxpart_g};
  hipLaunchCooperativeKernel((const void*)attn_persistent,
                             dim3(NBATCH * NBB), dim3(NT), args, 0, stream);
}

// Round 3
// 47344.437 us; speedup vs baseline: 2.2273x; 2.2273x over previous
//
#include <hip/hip_runtime.h>
#include <math.h>

// Location-sensitive attention scan, d-split persistent kernel.
// B=16, ENC_T=512, DEC_T=1024, D=512, KW=31, PAD=15.
// 256 blocks = 16 per batch element; block jb owns d-slice [32*jb, 32*jb+32),
// all 512 encoder positions. ONE fence-free cross-block exchange per step
// (relaxed agent-scope atomics through the LLC; no threadfence / buffer_wbl2).

#define NBB    16
#define NT     512
#define NBATCH 16
#define ENC_TT 512
#define DEC_TT 1024
#define DDIM   512
#define KWW    31
#define PADW   15
#define DB     32   // d's per block
#define CHT    32   // t's per thread chunk (16 chunks x 32 t = 512)

#define WS_CTR  0      // int ctr[16*32] (one cacheline-padded counter per b)
#define WS_PART 4096   // float[2][16][16][512] double-buffered logit partials

__device__ __forceinline__ float fast_tanh(float x) {
  x = fminf(10.f, fmaxf(-10.f, x));
  const float e = __expf(2.f * x);
  return (e - 1.f) * __builtin_amdgcn_rcpf(e + 1.f);  // err ~1e-6, way under tol
}

__global__ void __launch_bounds__(NT, 2)
attn_persistent(const float* __restrict__ enc,
                const float* __restrict__ mel,
                const int*   __restrict__ out_len,
                const float* __restrict__ w_lin,
                const float* __restrict__ w_conv,
                float* __restrict__ out_ctx,   // [16][1024][512]
                float* __restrict__ out_scr,   // [16][1024][512]
                int*   __restrict__ ctr,
                float* __restrict__ part)      // [2][16][16][512]
{
  const int tid   = threadIdx.x;
  const int b     = blockIdx.x / NBB;
  const int jb    = blockIdx.x % NBB;
  const int d0    = jb * DB;
  const int lane  = tid & 63;
  const int l31   = tid & 31;
  const int chunk = tid >> 5;          // 0..15
  const int wid   = tid >> 6;

  __shared__ float enc_T[DB][ENC_TT + 1];      // 32x513: enc[b,:,d-slice]^T
  __shared__ float s_arr[ENC_TT + 2 * PADW];   // prev score, zero halos
  __shared__ float c_arr[ENC_TT + 2 * PADW];   // cum score, zero halos
  __shared__ float q_lds[DB];                  // mask*mel + ctx for own d's
  __shared__ float ctx_lds[DB];
  __shared__ float red16[16][DB + 1];
  __shared__ float sm8[8];

  for (int i = tid; i < ENC_TT + 2 * PADW; i += NT) { s_arr[i] = 0.f; c_arr[i] = 0.f; }
  // transposed enc slice: consecutive tid -> consecutive d (coalesced 128B rows)
  for (int i = tid; i < DB * ENC_TT; i += NT) {
    const int t = i >> 5, dl = i & 31;
    enc_T[dl][t] = enc[((size_t)b * ENC_TT + t) * DDIM + d0 + dl];
  }
  // conv weights for my d (16x redundant across chunks, VGPR-resident)
  float w0[KWW], w1[KWW];
  const int dmy = d0 + l31;
#pragma unroll
  for (int k = 0; k < KWW; ++k) {
    w0[k] = w_conv[(size_t)dmy * (2 * KWW) + k];
    w1[k] = w_conv[(size_t)dmy * (2 * KWW) + KWW + k];
  }
  const float wld  = w_lin[dmy];
  const int   olen = out_len[b];
  if (tid < DB) {
    const float m0 = (0 < olen) ? 1.f : 0.f;
    q_lds[tid]   = m0 * mel[((size_t)b * DEC_TT + 0) * DDIM + d0 + tid];
    ctx_lds[tid] = 0.f;
  }
  __syncthreads();

  int* myctr = ctr + b * 32;

  for (int step = 0; step < DEC_TT; ++step) {
    // ---- Phase A: conv + tanh + wl for my d over my 32 t's (t=chunk*32+u) --
    float acc[CHT];
#pragma unroll
    for (int u = 0; u < CHT; ++u) acc[u] = 0.f;
    const int base = chunk * CHT;
#pragma unroll
    for (int j = 0; j < CHT + 2 * PADW; ++j) {   // 62 window positions
      const float sv = s_arr[base + j];          // uniform per half-wave
      const float cv = c_arr[base + j];
#pragma unroll
      for (int u = 0; u < CHT; ++u) {
        const int k = j - u;                     // compile-time after unroll
        if (k >= 0 && k < KWW) {
          acc[u] = fmaf(w0[k], sv, acc[u]);
          acc[u] = fmaf(w1[k], cv, acc[u]);
        }
      }
    }
    const float q = q_lds[l31];
#pragma unroll
    for (int u = 0; u < CHT; ++u) acc[u] = wld * fast_tanh(q + acc[u]);

    // compacting butterfly: reduce 32 t-values across 32 d-lanes, 31 shuffles.
    // invariant: entering level l, acc[i] = partial for u=(i<<l)|(l31&((1<<l)-1))
#pragma unroll
    for (int l = 0; l < 5; ++l) {
      const int  m  = 1 << l;
      const bool up = (l31 & m) != 0;
#pragma unroll
      for (int jj = 0; jj < (32 >> (l + 1)); ++jj) {
        const float keep = up ? acc[2 * jj + 1] : acc[2 * jj];
        const float send = up ? acc[2 * jj] : acc[2 * jj + 1];
        acc[jj] = keep + __shfl_xor(send, m, 64);
      }
    }
    // thread tid now holds partial logit for t = chunk*32 + l31 = tid
    const int buf = step & 1;
    float* pslot = &part[(((size_t)buf * NBATCH + b) * NBB + jb) * ENC_TT + tid];
    __hip_atomic_store(pslot, acc[0], __ATOMIC_RELAXED, __HIP_MEMORY_SCOPE_AGENT);

    __syncthreads();   // s_waitcnt vmcnt(0): sc1 stores have reached the LLC
    if (tid == 0) {
      __hip_atomic_fetch_add(myctr, 1, __ATOMIC_RELAXED, __HIP_MEMORY_SCOPE_AGENT);
      const int target = NBB * (step + 1);
      while (__hip_atomic_load(myctr, __ATOMIC_RELAXED, __HIP_MEMORY_SCOPE_AGENT) < target)
        __builtin_amdgcn_s_sleep(1);
    }
    __syncthreads();

    // ---- Phase B: sum 16 partials, softmax over 512 (redundant per block) --
    float lg = 0.f;
#pragma unroll
    for (int jj = 0; jj < NBB; ++jj)
      lg += __hip_atomic_load(&part[(((size_t)buf * NBATCH + b) * NBB + jj) * ENC_TT + tid],
                              __ATOMIC_RELAXED, __HIP_MEMORY_SCOPE_AGENT);
    float mx = lg;
#pragma unroll
    for (int m = 1; m < 64; m <<= 1) mx = fmaxf(mx, __shfl_xor(mx, m, 64));
    if (lane == 0) sm8[wid] = mx;
    __syncthreads();
    float t8 = sm8[lane & 7];
#pragma unroll
    for (int m = 1; m < 8; m <<= 1) t8 = fmaxf(t8, __shfl_xor(t8, m, 64));
    const float ex = __expf(lg - t8);
    float sum = ex;
#pragma unroll
    for (int m = 1; m < 64; m <<= 1) sum += __shfl_xor(sum, m, 64);
    __syncthreads();   // sm8 reuse
    if (lane == 0) sm8[wid] = sum;
    __syncthreads();
    float s8 = sm8[lane & 7];
#pragma unroll
    for (int m = 1; m < 8; m <<= 1) s8 += __shfl_xor(s8, m, 64);
    const float score = ex / s8;   // identical sequence in every block of b

    s_arr[PADW + tid] = score;
    c_arr[PADW + tid] += score;
    if (jb == 0) out_scr[((size_t)b * DEC_TT + step) * ENC_TT + tid] = score;
    __syncthreads();

    // ---- Phase C: ctx for own 32 d's ----
    float partc = 0.f;
#pragma unroll
    for (int i = 0; i < 32; ++i)
      partc = fmaf(s_arr[PADW + base + i], enc_T[l31][base + i], partc);
    red16[chunk][l31] = partc;
    __syncthreads();
    const float maskf = (step < olen) ? 1.f : 0.f;
    if (tid < DB) {
      float cx = 0.f;
#pragma unroll
      for (int jj = 0; jj < 16; ++jj) cx += red16[jj][tid];
      ctx_lds[tid] = cx;
      out_ctx[((size_t)b * DEC_TT + step) * DDIM + d0 + tid] = maskf * cx;
      if (step + 1 < DEC_TT) {
        const float mf2 = (step + 1 < olen) ? 1.f : 0.f;
        q_lds[tid] = mf2 * mel[((size_t)b * DEC_TT + (step + 1)) * DDIM + d0 + tid] + cx;
      }
    }
    __syncthreads();
  }
}

extern "C" void kernel_launch(void* const* d_in, const int* in_sizes, int n_in,
                              void* d_out, int out_size, void* d_ws, size_t ws_size,
                              hipStream_t stream) {
  const float* enc   = (const float*)d_in[0];
  const float* mel   = (const float*)d_in[1];
  const int*   olen  = (const int*)d_in[3];   // encoder_lengths (d_in[2]) unused
  const float* wlin  = (const float*)d_in[4];
  const float* wconv = (const float*)d_in[5];

  float* out_ctx = (float*)d_out;
  float* out_scr = out_ctx + (size_t)NBATCH * DEC_TT * DDIM;

  char* ws = (char*)d_ws;
  hipMemsetAsync(ws, 0, 4096, stream);  // zero barrier counters (ws is poisoned)

  int*   ctr  = (int*)(ws + WS_CTR);
  float* part = (float*)(ws + WS_PART);

  void* args[] = {&enc, &mel, &olen, &wlin, &wconv, &out_ctx, &out_scr, &ctr, &part};
  hipLaunchCooperativeKernel((const void*)attn_persistent,
                             dim3(NBATCH * NBB), dim3(NT), args, 0, stream);
}

// Round 6
// 22464.218 us; speedup vs baseline: 4.6942x; 2.1075x over previous
//
#include <hip/hip_runtime.h>
#include <math.h>

// Location-sensitive attention scan, d-split / t-owner persistent kernel.
// B=16, ENC_T=512, DEC_T=1024, D=512, KW=31, PAD=15.
// 256 co-resident blocks (hipLaunchCooperativeKernel), 16 per batch element;
// block jb owns d-slice [32*jb, 32*jb+32). Thread tid owns encoder position
// t=tid: score window in LDS, cum window in 31 VGPRs, conv weights via SGPRs.
//
// NUMERICS (R4/R5 lessons): the scan amplifies per-step rounding reorders
// super-linearly; outputs must bit-match the R3 ordering which passed at the
// 4.88e-4 comparison floor:
//  - conv: ONE accumulator, k ascending, s-term then c-term (R4: split chains
//    -> 1.45e-2 FAIL);
//  - logit d-sum: balanced binary tree over d-index with SEPARATELY ROUNDED
//    products wl*tanh (R5: sequential fmaf chain -> 4.15e-3 FAIL). Tree block
//    is contract(off) so t0+t1 can't contract into fma(wl,tanh,t1).
// ONE fence-free cross-block exchange per step (relaxed agent-scope atomics).

#define NBB    16
#define NT     512
#define NBATCH 16
#define ENC_TT 512
#define DEC_TT 1024
#define DDIM   512
#define KWW    31
#define PADW   15
#define DB     32   // d's per block

#define WS_CTR  0      // int ctr[16*32] (cacheline-padded counter per b)
#define WS_PART 4096   // float[2][16][16][512] double-buffered logit partials

__device__ __forceinline__ float fast_tanh(float x) {
  x = fminf(10.f, fmaxf(-10.f, x));
  const float e = __expf(2.f * x);
  return (e - 1.f) * __builtin_amdgcn_rcpf(e + 1.f);  // err ~1e-6 << 3.4e-3 tol
}

// conv for d = d0+dd at this thread's t: R3-exact order (k asc, s then c).
#define CONV_ACC(dd, out) do {                                   \
    const float* wr_ = wbase + (dd) * (2 * KWW);                 \
    float a_ = 0.f;                                              \
    _Pragma("unroll")                                            \
    for (int k_ = 0; k_ < KWW; ++k_) {                           \
      a_ = fmaf(wr_[k_],       s_win[k_], a_);                   \
      a_ = fmaf(wr_[KWW + k_], c_win[k_], a_);                   \
    }                                                            \
    out = a_;                                                    \
  } while (0)

__global__ void __launch_bounds__(NT, 2)
attn_persistent(const float* __restrict__ enc,
                const float* __restrict__ mel,
                const int*   __restrict__ out_len,
                const float* __restrict__ w_lin,
                const float* __restrict__ w_conv,
                float* __restrict__ out_ctx,   // [16][1024][512]
                float* __restrict__ out_scr,   // [16][1024][512]
                int*   __restrict__ ctr,
                float* __restrict__ part)      // [2][16][16][512]
{
  const int tid   = threadIdx.x;
  const int b     = blockIdx.x / NBB;
  const int jb    = blockIdx.x % NBB;
  const int d0    = jb * DB;
  const int lane  = tid & 63;
  const int l31   = tid & 31;
  const int chunk = tid >> 5;          // 0..15
  const int wid   = tid >> 6;

  __shared__ float enc_T[DB][ENC_TT + 1];      // 32x513: enc[b,:,d-slice]^T
  __shared__ float s_arr[ENC_TT + 2 * PADW];   // prev score, zero halos
  __shared__ float q_lds[DB];                  // mask*mel + ctx for own d's
  __shared__ float wl_lds[DB];
  __shared__ float red16[16][DB + 1];
  __shared__ float sm8[8];

  for (int i = tid; i < ENC_TT + 2 * PADW; i += NT) s_arr[i] = 0.f;
  for (int i = tid; i < DB * ENC_TT; i += NT) {    // coalesced 128B rows
    const int t = i >> 5, dl = i & 31;
    enc_T[dl][t] = enc[((size_t)b * ENC_TT + t) * DDIM + d0 + dl];
  }
  const int olen = out_len[b];
  if (tid < DB) {
    wl_lds[tid] = w_lin[d0 + tid];
    const float m0 = (0 < olen) ? 1.f : 0.f;
    q_lds[tid] = m0 * mel[((size_t)b * DEC_TT + 0) * DDIM + d0 + tid];
  }
  // cum-score conv window for my t, register-resident across all 1024 steps
  float c_win[KWW];
#pragma unroll
  for (int k = 0; k < KWW; ++k) c_win[k] = 0.f;

  const float* wbase = w_conv + (size_t)d0 * (2 * KWW);  // block-uniform
  int* myctr = ctr + b * 32;
  __syncthreads();

  for (int step = 0; step < DEC_TT; ++step) {
    // ---- Phase A: thread owns t=tid; 32 d's of this block ----
    // s_arr[PADW + (t-15) + k] == s_arr[tid + k]
    float s_win[KWW];
#pragma unroll
    for (int k = 0; k < KWW; ++k) {
      s_win[k] = s_arr[tid + k];
      c_win[k] += s_win[k];            // cum includes current score
    }
    float lg;
    {
#pragma clang fp contract(off)
      // terms wl[d]*tanh(q[d]+conv) summed as a balanced binary tree over
      // d-index -- bit-identical to R3's lane butterfly. contract(off) keeps
      // each product separately rounded (fmaf in CONV_ACC is unaffected).
      float lv1[16];
#pragma unroll
      for (int j = 0; j < 16; ++j) {
        float a0, a1;
        CONV_ACC(2 * j,     a0);
        CONV_ACC(2 * j + 1, a1);
        const float t0 = wl_lds[2 * j]     * fast_tanh(q_lds[2 * j]     + a0);
        const float t1 = wl_lds[2 * j + 1] * fast_tanh(q_lds[2 * j + 1] + a1);
        lv1[j] = t0 + t1;
      }
      float lv2[8];
#pragma unroll
      for (int j = 0; j < 8; ++j) lv2[j] = lv1[2 * j] + lv1[2 * j + 1];
      float lv3[4];
#pragma unroll
      for (int j = 0; j < 4; ++j) lv3[j] = lv2[2 * j] + lv2[2 * j + 1];
      const float lv4a = lv3[0] + lv3[1];
      const float lv4b = lv3[2] + lv3[3];
      lg = lv4a + lv4b;
    }

    // ---- exchange: post partial logit, one barrier per step ----
    const int buf = step & 1;
    float* pslot = &part[(((size_t)buf * NBATCH + b) * NBB + jb) * ENC_TT + tid];
    __hip_atomic_store(pslot, lg, __ATOMIC_RELAXED, __HIP_MEMORY_SCOPE_AGENT);
    __syncthreads();   // drains this wave's stores (vmcnt(0)) before the post
    if (tid == 0) {
      __hip_atomic_fetch_add(myctr, 1, __ATOMIC_RELAXED, __HIP_MEMORY_SCOPE_AGENT);
      const int target = NBB * (step + 1);
      while (__hip_atomic_load(myctr, __ATOMIC_RELAXED, __HIP_MEMORY_SCOPE_AGENT) < target)
        __builtin_amdgcn_s_sleep(1);
    }
    __syncthreads();

    // ---- Phase B: sum 16 partials, softmax over 512 (redundant per block) --
    float lgt = 0.f;
#pragma unroll
    for (int jj = 0; jj < NBB; ++jj)
      lgt += __hip_atomic_load(&part[(((size_t)buf * NBATCH + b) * NBB + jj) * ENC_TT + tid],
                               __ATOMIC_RELAXED, __HIP_MEMORY_SCOPE_AGENT);
    float mx = lgt;
#pragma unroll
    for (int m = 1; m < 64; m <<= 1) mx = fmaxf(mx, __shfl_xor(mx, m, 64));
    if (lane == 0) sm8[wid] = mx;
    __syncthreads();
    float t8 = sm8[lane & 7];
#pragma unroll
    for (int m = 1; m < 8; m <<= 1) t8 = fmaxf(t8, __shfl_xor(t8, m, 64));
    const float ex = __expf(lgt - t8);
    float sum = ex;
#pragma unroll
    for (int m = 1; m < 64; m <<= 1) sum += __shfl_xor(sum, m, 64);
    __syncthreads();   // sm8 reuse
    if (lane == 0) sm8[wid] = sum;
    __syncthreads();
    float s8 = sm8[lane & 7];
#pragma unroll
    for (int m = 1; m < 8; m <<= 1) s8 += __shfl_xor(s8, m, 64);
    const float score = ex / s8;     // identical sequence in every block of b

    s_arr[PADW + tid] = score;
    if (jb == 0) out_scr[((size_t)b * DEC_TT + step) * ENC_TT + tid] = score;
    __syncthreads();

    // ---- Phase C: ctx for own 32 d's (thread <-> (chunk, d-local)) ----
    const int base = chunk * 32;
    float partc = 0.f;
#pragma unroll
    for (int i = 0; i < 32; ++i)
      partc = fmaf(s_arr[PADW + base + i], enc_T[l31][base + i], partc);
    red16[chunk][l31] = partc;
    __syncthreads();
    const float maskf = (step < olen) ? 1.f : 0.f;
    if (tid < DB) {
      float cx = 0.f;
#pragma unroll
      for (int jj = 0; jj < 16; ++jj) cx += red16[jj][tid];
      out_ctx[((size_t)b * DEC_TT + step) * DDIM + d0 + tid] = maskf * cx;
      if (step + 1 < DEC_TT) {
        const float mf2 = (step + 1 < olen) ? 1.f : 0.f;
        q_lds[tid] = mf2 * mel[((size_t)b * DEC_TT + (step + 1)) * DDIM + d0 + tid] + cx;
      }
    }
    __syncthreads();
  }
}

extern "C" void kernel_launch(void* const* d_in, const int* in_sizes, int n_in,
                              void* d_out, int out_size, void* d_ws, size_t ws_size,
                              hipStream_t stream) {
  const float* enc   = (const float*)d_in[0];
  const float* mel   = (const float*)d_in[1];
  const int*   olen  = (const int*)d_in[3];   // encoder_lengths (d_in[2]) unused
  const float* wlin  = (const float*)d_in[4];
  const float* wconv = (const float*)d_in[5];

  float* out_ctx = (float*)d_out;
  float* out_scr = out_ctx + (size_t)NBATCH * DEC_TT * DDIM;

  char* ws = (char*)d_ws;
  hipMemsetAsync(ws, 0, 4096, stream);  // zero barrier counters (ws is poisoned)

  int*   ctr  = (int*)(ws + WS_CTR);
  float* part = (float*)(ws + WS_PART);

  void* args[] = {&enc, &mel, &olen, &wlin, &wconv, &out_ctx, &out_scr, &ctr, &part};
  hipLaunchCooperativeKernel((const void*)attn_persistent,
                             dim3(NBATCH * NBB), dim3(NT), args, 0, stream);
}

// Round 9
// 14482.635 us; speedup vs baseline: 7.2813x; 1.5511x over previous
//
#include <hip/hip_runtime.h>
#include <math.h>

// Location-sensitive attention scan — MULTI-LAUNCH version. B=16, ENC_T=512,
// DEC_T=1024, D=512, KW=31, PAD=15.
// R8 post-mortem: first validation passed BIT-EXACT (4.88e-4) but the
// graph-replay re-validation failed -> replay nondeterminism in the custom
// relaxed-atomic exchange / cooperative spin barrier. Response: remove ALL
// custom sync. 1025 chained plain launches (one per step + epilogue); kernel
// boundaries give dispatch-level coherence; cross-launch state in d_ws via
// double-buffered part[2]/cum[2] (launch s reads buf[s&1], writes
// buf[(s+1)&1] -- disjoint, race-free by construction). Fully deterministic.
//
// NUMERICS: every FP op keeps the R6/R8-proven order (passed at the 4.88e-4
// floor): conv = one accumulator, k ascending, s-then-c (fmaf); logit d-sum =
// compacting lane butterfly (balanced tree, separately-rounded products,
// contract(off)); cum = one add/step ascending; softmax/ctx trees verbatim;
// q = fmaf(mask, mel, ctx) matching R6's contracted mul+add.

#define NBB    16
#define NT     512
#define NBATCH 16
#define ENC_TT 512
#define DEC_TT 1024
#define DDIM   512
#define KWW    31
#define PADW   15
#define DB     32   // d's per block

__device__ __forceinline__ float fast_tanh(float x) {
  x = fminf(10.f, fmaxf(-10.f, x));
  const float e = __expf(2.f * x);
  return (e - 1.f) * __builtin_amdgcn_rcpf(e + 1.f);  // err ~1e-6 << 3.4e-3 tol
}

__global__ void __launch_bounds__(NT, 2)
attn_step(const float* __restrict__ enc,
          const float* __restrict__ mel,
          const int*   __restrict__ out_len,
          const float* __restrict__ w_lin,
          const float* __restrict__ w_conv,
          float* __restrict__ out_ctx,   // [16][1024][512]
          float* __restrict__ out_scr,   // [16][1024][512]
          float* __restrict__ part,      // [2][16][16][512] logit partials
          float* __restrict__ cum,       // [2][16][512] cumulative scores
          int step)                      // 0..1024
{
  const int tid   = threadIdx.x;
  const int b     = blockIdx.x / NBB;
  const int jb    = blockIdx.x % NBB;
  const int d0    = jb * DB;
  const int lane  = tid & 63;
  const int l31   = tid & 31;    // Phase A: my d within slice; C: d-local
  const int chunk = tid >> 5;    // Phase A: first owned 8-t chunk; C: 32-t chunk
  const int wid   = tid >> 6;

  __shared__ float s_arr[ENC_TT + 2 * PADW];   // prev score, zero halos
  __shared__ float c_arr[ENC_TT + 2 * PADW];   // cum score, zero halos
  __shared__ float q_lds[DB];                  // mask*mel + ctx for own d's
  __shared__ float red16[16][DB + 1];
  __shared__ float sm8[8];

  for (int i = tid; i < ENC_TT + 2 * PADW; i += NT) { s_arr[i] = 0.f; c_arr[i] = 0.f; }

  // conv weights + w_lin for my d: VGPR-resident (R8-proven Phase A layout)
  float w0[KWW], w1[KWW];
  {
    const float* wr = w_conv + (size_t)(d0 + l31) * (2 * KWW);
#pragma unroll
    for (int k = 0; k < KWW; ++k) { w0[k] = wr[k]; w1[k] = wr[KWW + k]; }
  }
  const float wl_d = w_lin[d0 + l31];
  const int   olen = out_len[b];
  __syncthreads();   // s_arr/c_arr zeroed before any use/overwrite

  if (step > 0) {
    // ---- finish step-1: sum 16 partials, softmax over 512 (R6-verbatim) ---
    const float* pin = part + ((size_t)((step - 1) & 1) * NBATCH + b) * NBB * ENC_TT;
    float lgt = 0.f;
#pragma unroll
    for (int jj = 0; jj < NBB; ++jj) lgt += pin[jj * ENC_TT + tid];
    float mx = lgt;
#pragma unroll
    for (int m = 1; m < 64; m <<= 1) mx = fmaxf(mx, __shfl_xor(mx, m, 64));
    if (lane == 0) sm8[wid] = mx;
    __syncthreads();
    float t8 = sm8[lane & 7];
#pragma unroll
    for (int m = 1; m < 8; m <<= 1) t8 = fmaxf(t8, __shfl_xor(t8, m, 64));
    const float ex = __expf(lgt - t8);
    float sum = ex;
#pragma unroll
    for (int m = 1; m < 64; m <<= 1) sum += __shfl_xor(sum, m, 64);
    __syncthreads();   // sm8 reuse
    if (lane == 0) sm8[wid] = sum;
    __syncthreads();
    float s8 = sm8[lane & 7];
#pragma unroll
    for (int m = 1; m < 8; m <<= 1) s8 += __shfl_xor(s8, m, 64);
    const float score = ex / s8;   // identical sequence in every block of b

    s_arr[PADW + tid] = score;
    const float cu = cum[((size_t)(step & 1) * NBATCH + b) * ENC_TT + tid] + score;
    c_arr[PADW + tid] = cu;        // cum through step-1 (same add chain as R6)
    if (jb == 0) {
      out_scr[((size_t)b * DEC_TT + (step - 1)) * ENC_TT + tid] = score;
      cum[((size_t)((step + 1) & 1) * NBATCH + b) * ENC_TT + tid] = cu;
    }
    __syncthreads();

    // ---- ctx for step-1: own 32 d's, direct L2-hot enc reads (coalesced) --
    const int base = chunk * 32;
    float partc = 0.f;
#pragma unroll
    for (int i = 0; i < 32; ++i)
      partc = fmaf(s_arr[PADW + base + i],
                   enc[((size_t)b * ENC_TT + base + i) * DDIM + d0 + l31], partc);
    red16[chunk][l31] = partc;
    __syncthreads();
    const float maskf = ((step - 1) < olen) ? 1.f : 0.f;
    if (tid < DB) {
      float cx = 0.f;
#pragma unroll
      for (int jj = 0; jj < 16; ++jj) cx += red16[jj][tid];
      out_ctx[((size_t)b * DEC_TT + (step - 1)) * DDIM + d0 + tid] = maskf * cx;
      if (step < DEC_TT) {
        const float mf2 = (step < olen) ? 1.f : 0.f;
        q_lds[tid] = fmaf(mf2, mel[((size_t)b * DEC_TT + step) * DDIM + d0 + tid], cx);
      }
    }
    __syncthreads();
  } else {
    // step 0: scores/cum are zero; q = masked mel_0; zero-init cum[1] for s=1
    if (tid < DB) {
      const float m0 = (0 < olen) ? 1.f : 0.f;
      q_lds[tid] = m0 * mel[((size_t)b * DEC_TT + 0) * DDIM + d0 + tid];
    }
    if (jb == 0) cum[((size_t)1 * NBATCH + b) * ENC_TT + tid] = 0.f;
    __syncthreads();
  }

  if (step < DEC_TT) {
    // ---- Phase A (R8-verbatim, bit-exact-verified): conv + tanh + wl + tree
    const float q_d = q_lds[l31];
    float* pout = part + (((size_t)(step & 1) * NBATCH + b) * NBB + jb) * ENC_TT;
#pragma unroll
    for (int ci = 0; ci < 4; ++ci) {
      const int cc = chunk + 16 * ci;          // 8-t chunk index [0,64)
      const int tb = cc * 8;                   // halo coords: s(t)=s_arr[PADW+t]
      float acc[8];
#pragma unroll
      for (int u = 0; u < 8; ++u) acc[u] = 0.f;
      // per acc[u]: k ascending, s-term then c-term (R6's CONV_ACC order)
#pragma unroll
      for (int p = 0; p < 8 + 2 * PADW; ++p) {
        const float sv = s_arr[tb + p];
        const float cv = c_arr[tb + p];
#pragma unroll
        for (int u = 0; u < 8; ++u) {
          const int k = p - u;                 // compile-time after unroll
          if (k >= 0 && k < KWW) {
            acc[u] = fmaf(w0[k], sv, acc[u]);
            acc[u] = fmaf(w1[k], cv, acc[u]);
          }
        }
      }
      {
#pragma clang fp contract(off)
        // separately-rounded products, balanced binary tree over d
#pragma unroll
        for (int u = 0; u < 8; ++u) acc[u] = wl_d * fast_tanh(q_d + acc[u]);
        {
          const bool up = (l31 & 1) != 0;      // m=1: 8 -> 4
#pragma unroll
          for (int jj = 0; jj < 4; ++jj) {
            const float keep = up ? acc[2 * jj + 1] : acc[2 * jj];
            const float send = up ? acc[2 * jj] : acc[2 * jj + 1];
            acc[jj] = keep + __shfl_xor(send, 1, 64);
          }
        }
        {
          const bool up = (l31 & 2) != 0;      // m=2: 4 -> 2
#pragma unroll
          for (int jj = 0; jj < 2; ++jj) {
            const float keep = up ? acc[2 * jj + 1] : acc[2 * jj];
            const float send = up ? acc[2 * jj] : acc[2 * jj + 1];
            acc[jj] = keep + __shfl_xor(send, 2, 64);
          }
        }
        {
          const bool up = (l31 & 4) != 0;      // m=4: 2 -> 1
          const float keep = up ? acc[1] : acc[0];
          const float send = up ? acc[0] : acc[1];
          acc[0] = keep + __shfl_xor(send, 4, 64);
        }
        acc[0] = acc[0] + __shfl_xor(acc[0], 8, 64);
        acc[0] = acc[0] + __shfl_xor(acc[0], 16, 64);
      }
      if (l31 < 8) pout[tb + l31] = acc[0];    // lane holds t = tb + l31
    }
  }
}

extern "C" void kernel_launch(void* const* d_in, const int* in_sizes, int n_in,
                              void* d_out, int out_size, void* d_ws, size_t ws_size,
                              hipStream_t stream) {
  const float* enc   = (const float*)d_in[0];
  const float* mel   = (const float*)d_in[1];
  const int*   olen  = (const int*)d_in[3];   // encoder_lengths (d_in[2]) unused
  const float* wlin  = (const float*)d_in[4];
  const float* wconv = (const float*)d_in[5];

  float* out_ctx = (float*)d_out;
  float* out_scr = out_ctx + (size_t)NBATCH * DEC_TT * DDIM;

  float* part = (float*)d_ws;                                   // 1 MB
  float* cum  = part + (size_t)2 * NBATCH * NBB * ENC_TT;       // 64 KB

  for (int s = 0; s <= DEC_TT; ++s) {
    attn_step<<<dim3(NBATCH * NBB), dim3(NT), 0, stream>>>(
        enc, mel, olen, wlin, wconv, out_ctx, out_scr, part, cum, s);
  }
}